// Round 2
// baseline (224.560 us; speedup 1.0000x reference)
//
#include <hip/hip_runtime.h>

#define HH 384
#define WW 384
#define OUTD 370
#define NSHIFT 99

// ---- fused per-tile geometry: 32 wide x 24 tall (R13, measured 190us/90% VALU) ----
// R15: VALUBusy~94 is issue-side, not exec (hand count ~72us exec vs 187us wall ->
// ~45% true VALU util). Latency/occupancy-bound: grid 768 = 3 blocks/CU caps
// residency; LDS 31KB allows 5/CU. Fix: split the 99-shift loop over blockIdx.z
// (2 halves) as TWO kernels (p1: min/V partials to ws, p2: combine + loss),
// 1536 blocks each -> ~5 blocks/CU resident.
// R16: R15 bench died (container failed twice) -- prime suspect: p1 wrote 14.2MB
// into d_ws without checking ws_size -> OOB global writes -> GPU hang. Now gated:
// ws_size >= WS_NEED_BYTES or fall back to the proven single-kernel path.
// Bank law unchanged (R14-verified: 0 conflicts): LSTR==15 mod 32, TMS==-1 mod 32,
// horiz phases pure-image (P tid 0..119, G tid 128..247), residues 15*hr+8*oct
// bijective. Scalar VALU only -- packed v2f is FLOP-neutral on CDNA4 (R6, R14).
// z=0 shift range [45,95) contains all 4 cardinals in ORIGINAL order -> vsum is
// bitwise-identical to the single-kernel version; dmin is exact under min-split.
#define TW 32
#define TH 24
#define LSTR 47          // L stride (==15 mod 32)
#define LROWS 39         // 24 + 6 conv + 9 shift span
#define LPADSZ 1856      // 39*47=1833 padded to 32-mult -> LG base bank-aligned
#define TMS 31           // tmp_T stride (==-1 mod 32)
#define TTSZ (TW * TMS)  // 992 (32-mult)
#define NXT 12
#define NYT 16

#define G0 0.32465246735834974f   // exp(-9/8)
#define G1 0.6065306597126334f    // exp(-4/8)
#define G2 0.8824969025845955f    // exp(-1/8)
#define KS 0.039788735772973836f  // 1/(8*pi)
#define LOG2E 1.4426950408889634f

// ---- workspace layout (floats) ----
// dmw[z][b][img][y*WW+x] : 2*4*2*HH*WW   (per-z-half partial min over its shifts)
// vsw[b][img][y*WW+x]    : 4*2*HH*WW     (full cardinal sum, produced by z=0)
#define IMG_PIX (HH * WW)
#define DMW_SZ (2 * 4 * 2 * IMG_PIX)
#define VSW_SZ (4 * 2 * IMG_PIX)
#define WS_NEED_BYTES ((size_t)(DMW_SZ + VSW_SZ) * sizeof(float))  // 14,155,776

__device__ __forceinline__ float tap7(const float* v)
{
    return fmaf(G0, v[0] + v[6],
           fmaf(G1, v[1] + v[5],
           fmaf(G2, v[2] + v[4], v[3])));
}

__device__ __forceinline__ void shift_of(int s, int& sx, int& sy)
{
    int t = (s < 55) ? s : s + 1;    // skip (0,0)
    sx = t / 10 - 5;
    sy = t - (t / 10) * 10 - 5;
}

__device__ __forceinline__ void load_tile(const float* __restrict__ img,
                                          int oy0, int ox0, float* L, int tid)
{
    for (int i = tid; i < LROWS * LSTR; i += 256) {
        int r = i / LSTR, c = i - r * LSTR;
        int gr = oy0 + r; if (gr >= HH) gr -= HH;   // circular wrap
        int gc = ox0 + c; if (gc >= WW) gc -= WW;
        L[i] = img[gr * WW + gc];
    }
}

// horizontal 7-tap over inline diff^2; 8 outputs -> transposed tmp (R13 scalar core)
__device__ __forceinline__ void horiz8(const float* __restrict__ Lb,
                                       const float* __restrict__ cA,
                                       float* __restrict__ tb,
                                       int r, int c0, int sx, int sy)
{
    const float* Ls = &Lb[(r + 4 - sy) * LSTR + (c0 + 4 - sx)];
    float v[14];
#pragma unroll
    for (int t = 0; t < 14; ++t) { float d = cA[t] - Ls[t]; v[t] = d * d; }
    float* o = &tb[c0 * TMS + r];
#pragma unroll
    for (int k = 0; k < 8; ++k) o[k * TMS] = tap7(v + k);
}

// vertical 7-tap, 3 outputs from 9 consecutive tmp_T values (R13 scalar core)
__device__ __forceinline__ void vert3(const float* __restrict__ tT, int vx, int vy0, float* D)
{
    const float* t = &tT[vx * TMS + vy0];
    float w[9];
#pragma unroll
    for (int j = 0; j < 9; ++j) w[j] = t[j];
#pragma unroll
    for (int k = 0; k < 3; ++k) D[k] = KS * tap7(w + k);
}

// ---- phase 1 kernel: per-z-half partial min(D) and (z=0) cardinal V-sum ----
extern "C" __global__ void __launch_bounds__(256, 3)
mind_p1(const float* __restrict__ pred, const float* __restrict__ gt,
        float* __restrict__ ws)
{
    __shared__ float LP[LPADSZ];
    __shared__ float LG[LPADSZ];
    __shared__ float tTP[2][TTSZ];
    __shared__ float tTG[2][TTSZ];
    const int tid = threadIdx.x;
    const int b = blockIdx.y;
    const int z = blockIdx.z;
    const int oy0 = ((int)blockIdx.x / NXT) * TH;
    const int ox0 = ((int)blockIdx.x % NXT) * TW;

    load_tile(pred + (size_t)b * IMG_PIX, oy0, ox0, LP, tid);
    load_tile(gt   + (size_t)b * IMG_PIX, oy0, ox0, LG, tid);

    const bool hP = tid < 120;
    const bool hG = (tid >= 128) && (tid < 248);
    const bool hasH = hP || hG;
    const int hu = hP ? tid : (tid - 128);
    const int hr = hu >> 2, hc0 = (hu & 3) << 3;
    const float* Lh = hG ? LG : LP;
    float* const tb0 = hG ? tTG[0] : tTP[0];
    float* const tb1 = hG ? tTG[1] : tTP[1];

    const int vx = tid & 31, vy0 = (tid >> 5) * 3;

    __syncthreads();

    float cA[14];
    if (hasH) {
        const float* p = &Lh[(hr + 4) * LSTR + hc0 + 4];
#pragma unroll
        for (int t = 0; t < 14; ++t) cA[t] = p[t];
    }

    float dmp[3], vsp[3], dmg[3], vsg[3];
#pragma unroll
    for (int k = 0; k < 3; ++k) { dmp[k] = 1e30f; vsp[k] = 0.f; dmg[k] = 1e30f; vsg[k] = 0.f; }

    // z=0: s in [45,95) (50 shifts, contains cardinals 45,54,55,64 in ascending
    // order -> vsum order identical to original). z=1: [0,45) u [95,99) (49).
    const int nS = z ? 49 : 50;
    for (int i = 0; i < nS; ++i) {
        const int s = z ? (i < 45 ? i : i + 50) : (45 + i);
        int sx, sy; shift_of(s, sx, sy);
        if (hasH) horiz8(Lh, cA, (i & 1) ? tb1 : tb0, hr, hc0, sx, sy);
        __syncthreads();   // tT[i&1] ready; buffer alternation -> WAR safe
        float Dp[3], Dg[3];
        vert3(tTP[i & 1], vx, vy0, Dp);
        vert3(tTG[i & 1], vx, vy0, Dg);
        if (z == 0) {
            const bool card = (sx * sx + sy * sy) == 1;
#pragma unroll
            for (int k = 0; k < 3; ++k) {
                dmp[k] = fminf(dmp[k], Dp[k]);
                dmg[k] = fminf(dmg[k], Dg[k]);
                if (card) { vsp[k] += Dp[k]; vsg[k] += Dg[k]; }
            }
        } else {
#pragma unroll
            for (int k = 0; k < 3; ++k) {
                dmp[k] = fminf(dmp[k], Dp[k]);
                dmg[k] = fminf(dmg[k], Dg[k]);
            }
        }
    }

    float* dmw = ws;
    float* vsw = ws + DMW_SZ;
#pragma unroll
    for (int k = 0; k < 3; ++k) {
        const int y = oy0 + vy0 + k, x = ox0 + vx;   // y,x <= 383, no wrap
        const int pix = y * WW + x;
        dmw[((z * 4 + b) * 2 + 0) * IMG_PIX + pix] = dmp[k];
        dmw[((z * 4 + b) * 2 + 1) * IMG_PIX + pix] = dmg[k];
        if (z == 0) {
            vsw[(b * 2 + 0) * IMG_PIX + pix] = vsp[k];
            vsw[(b * 2 + 1) * IMG_PIX + pix] = vsg[k];
        }
    }
}

// ---- phase 2 kernel: combine partials, recompute D for z-half, accumulate loss ----
extern "C" __global__ void __launch_bounds__(256, 3)
mind_p2(const float* __restrict__ pred, const float* __restrict__ gt,
        const float* __restrict__ ws, float* __restrict__ out)
{
    __shared__ float LP[LPADSZ];
    __shared__ float LG[LPADSZ];
    __shared__ float tTP[2][TTSZ];
    __shared__ float tTG[2][TTSZ];
    __shared__ float wred[4];
    const int tid = threadIdx.x;
    const int b = blockIdx.y;
    const int z = blockIdx.z;
    const int oy0 = ((int)blockIdx.x / NXT) * TH;
    const int ox0 = ((int)blockIdx.x % NXT) * TW;

    load_tile(pred + (size_t)b * IMG_PIX, oy0, ox0, LP, tid);
    load_tile(gt   + (size_t)b * IMG_PIX, oy0, ox0, LG, tid);

    const bool hP = tid < 120;
    const bool hG = (tid >= 128) && (tid < 248);
    const bool hasH = hP || hG;
    const int hu = hP ? tid : (tid - 128);
    const int hr = hu >> 2, hc0 = (hu & 3) << 3;
    const float* Lh = hG ? LG : LP;
    float* const tb0 = hG ? tTG[0] : tTP[0];
    float* const tb1 = hG ? tTG[1] : tTP[1];

    const int vx = tid & 31, vy0 = (tid >> 5) * 3;

    // combine partials (global loads issued early, hidden under load_tile/horiz)
    const float* dmw = ws;
    const float* vsw = ws + DMW_SZ;
    float dmp[3], dmg[3], rvp[3], rvg[3];
#pragma unroll
    for (int k = 0; k < 3; ++k) {
        const int y = oy0 + vy0 + k, x = ox0 + vx;
        const int pix = y * WW + x;
        const float dp0 = dmw[((0 * 4 + b) * 2 + 0) * IMG_PIX + pix];
        const float dp1 = dmw[((1 * 4 + b) * 2 + 0) * IMG_PIX + pix];
        const float dg0 = dmw[((0 * 4 + b) * 2 + 1) * IMG_PIX + pix];
        const float dg1 = dmw[((1 * 4 + b) * 2 + 1) * IMG_PIX + pix];
        dmp[k] = fminf(dp0, dp1);
        dmg[k] = fminf(dg0, dg1);
        const float vp = vsw[(b * 2 + 0) * IMG_PIX + pix];
        const float vg = vsw[(b * 2 + 1) * IMG_PIX + pix];
        // invalid pixels get rv=0 -> ep=eg=exp2(0)=1 -> |ep-eg|=0 exactly (branchless)
        const bool valid = (y < OUTD) && (x < OUTD);
        rvp[k] = valid ? LOG2E / (vp * 0.25f + 1e-5f) : 0.f;
        rvg[k] = valid ? LOG2E / (vg * 0.25f + 1e-5f) : 0.f;
    }

    __syncthreads();

    float cA[14];
    if (hasH) {
        const float* p = &Lh[(hr + 4) * LSTR + hc0 + 4];
#pragma unroll
        for (int t = 0; t < 14; ++t) cA[t] = p[t];
    }

    float acc = 0.f;
    const int s0 = z ? 50 : 0, s1 = z ? NSHIFT : 50;
    for (int s = s0; s < s1; ++s) {
        int sx, sy; shift_of(s, sx, sy);
        if (hasH) horiz8(Lh, cA, (s & 1) ? tb1 : tb0, hr, hc0, sx, sy);
        __syncthreads();
        float Dp[3], Dg[3];
        vert3(tTP[s & 1], vx, vy0, Dp);
        vert3(tTG[s & 1], vx, vy0, Dg);
#pragma unroll
        for (int k = 0; k < 3; ++k) {
            float ep = exp2f((dmp[k] - Dp[k]) * rvp[k]);
            float eg = exp2f((dmg[k] - Dg[k]) * rvg[k]);
            acc += fabsf(ep - eg);
        }
    }

#pragma unroll
    for (int off = 32; off > 0; off >>= 1) acc += __shfl_down(acc, off, 64);
    const int lane = tid & 63, wv = tid >> 6;
    if (lane == 0) wred[wv] = acc;
    __syncthreads();
    if (tid == 0) {
        const float SC = (float)(1.0 / 54212400.0);  // 1/(4*370*370*99)
        atomicAdd(out, (wred[0] + wred[1] + wred[2] + wred[3]) * SC);
    }
}

// ---- fallback: proven single-kernel fused path (R13/R14, 190us) ----
extern "C" __global__ void __launch_bounds__(256, 3)
mind_fused(const float* __restrict__ pred, const float* __restrict__ gt,
           float* __restrict__ out)
{
    __shared__ float LP[LPADSZ];
    __shared__ float LG[LPADSZ];
    __shared__ float tTP[2][TTSZ];
    __shared__ float tTG[2][TTSZ];
    __shared__ float wred[4];
    const int tid = threadIdx.x;
    const int b = blockIdx.y;
    const int oy0 = ((int)blockIdx.x / NXT) * TH;
    const int ox0 = ((int)blockIdx.x % NXT) * TW;

    load_tile(pred + (size_t)b * HH * WW, oy0, ox0, LP, tid);
    load_tile(gt   + (size_t)b * HH * WW, oy0, ox0, LG, tid);

    const bool hP = tid < 120;
    const bool hG = (tid >= 128) && (tid < 248);
    const bool hasH = hP || hG;
    const int hu = hP ? tid : (tid - 128);
    const int hr = hu >> 2, hc0 = (hu & 3) << 3;
    const float* Lh = hG ? LG : LP;
    float* const tb0 = hG ? tTG[0] : tTP[0];
    float* const tb1 = hG ? tTG[1] : tTP[1];

    const int vx = tid & 31, vy0 = (tid >> 5) * 3;

    __syncthreads();

    float cA[14];
    if (hasH) {
        const float* p = &Lh[(hr + 4) * LSTR + hc0 + 4];
#pragma unroll
        for (int t = 0; t < 14; ++t) cA[t] = p[t];
    }

    float dmp[3], vsp[3], dmg[3], vsg[3];
#pragma unroll
    for (int k = 0; k < 3; ++k) { dmp[k] = 1e30f; vsp[k] = 0.f; dmg[k] = 1e30f; vsg[k] = 0.f; }

    for (int s = 0; s < NSHIFT; ++s) {
        int sx, sy; shift_of(s, sx, sy);
        if (hasH) horiz8(Lh, cA, (s & 1) ? tb1 : tb0, hr, hc0, sx, sy);
        __syncthreads();
        float Dp[3], Dg[3];
        vert3(tTP[s & 1], vx, vy0, Dp);
        vert3(tTG[s & 1], vx, vy0, Dg);
        const bool card = (sx * sx + sy * sy) == 1;
#pragma unroll
        for (int k = 0; k < 3; ++k) {
            dmp[k] = fminf(dmp[k], Dp[k]);
            dmg[k] = fminf(dmg[k], Dg[k]);
            if (card) { vsp[k] += Dp[k]; vsg[k] += Dg[k]; }
        }
    }

    float rvp[3], rvg[3];
#pragma unroll
    for (int k = 0; k < 3; ++k) {
        int oy = oy0 + vy0 + k, ox = ox0 + vx;
        const bool valid = (oy < OUTD) && (ox < OUTD);
        rvp[k] = valid ? LOG2E / (vsp[k] * 0.25f + 1e-5f) : 0.f;
        rvg[k] = valid ? LOG2E / (vsg[k] * 0.25f + 1e-5f) : 0.f;
    }

    __syncthreads();

    float acc = 0.f;
    for (int s = 0; s < NSHIFT; ++s) {
        int sx, sy; shift_of(s, sx, sy);
        if (hasH) horiz8(Lh, cA, (s & 1) ? tb1 : tb0, hr, hc0, sx, sy);
        __syncthreads();
        float Dp[3], Dg[3];
        vert3(tTP[s & 1], vx, vy0, Dp);
        vert3(tTG[s & 1], vx, vy0, Dg);
#pragma unroll
        for (int k = 0; k < 3; ++k) {
            float ep = exp2f((dmp[k] - Dp[k]) * rvp[k]);
            float eg = exp2f((dmg[k] - Dg[k]) * rvg[k]);
            acc += fabsf(ep - eg);
        }
    }

#pragma unroll
    for (int off = 32; off > 0; off >>= 1) acc += __shfl_down(acc, off, 64);
    const int lane = tid & 63, wv = tid >> 6;
    if (lane == 0) wred[wv] = acc;
    __syncthreads();
    if (tid == 0) {
        const float SC = (float)(1.0 / 54212400.0);  // 1/(4*370*370*99)
        atomicAdd(out, (wred[0] + wred[1] + wred[2] + wred[3]) * SC);
    }
}

extern "C" void kernel_launch(void* const* d_in, const int* in_sizes, int n_in,
                              void* d_out, int out_size, void* d_ws, size_t ws_size,
                              hipStream_t stream)
{
    (void)in_sizes; (void)n_in; (void)out_size;
    const float* pred = (const float*)d_in[0];
    const float* gt   = (const float*)d_in[1];
    float* out = (float*)d_out;

    hipMemsetAsync(d_out, 0, sizeof(float), stream);

    if (d_ws != nullptr && ws_size >= WS_NEED_BYTES) {
        float* ws = (float*)d_ws;   // every word read by p2 is written by p1
        dim3 g(NXT * NYT, 4, 2);    // 192 tiles x 4 batch x 2 halves = 1536 blocks
        mind_p1<<<g, 256, 0, stream>>>(pred, gt, ws);
        mind_p2<<<g, 256, 0, stream>>>(pred, gt, ws, out);
    } else {
        dim3 g(NXT * NYT, 4, 1);    // proven fallback: 768 blocks = 3/CU
        mind_fused<<<g, 256, 0, stream>>>(pred, gt, out);
    }
}

// Round 3
// 217.604 us; speedup vs baseline: 1.0320x; 1.0320x over previous
//
#include <hip/hip_runtime.h>

#define HH 384
#define WW 384
#define OUTD 370
#define NSHIFT 99

// ---- fused per-tile geometry: 32 wide x 24 tall (R13, measured 190us) ----
// R15/R16 post-mortem: z-split doubled grid, occupancy 30->40%, VALUBusy ~100,
// time UNCHANGED (per-CU block-iter throughput pinned at ~800/us both ways).
// No single pipe saturated by hand count (VALU ~40%, LDS ~50% duty) ->
// the pin is the barrier-lockstep micro-phase structure: 198 barriers/block,
// each with full lgkmcnt drain + cold LDS-read restart, ~300 issue-cy/wave
// per phase -- too small a quantum to overlap VALU/LDS/latency.
// R17: TWO shifts per barrier period (4 tmp buffers/image, 46.6KB LDS, still
// 3 blocks/CU). Barrier count 198 -> 100, phase quantum x2, same instr count.
// Bank law unchanged (R14-verified 0 conflicts): LSTR==15 mod 32, TMS==-1 mod 32,
// horiz phases pure-image (P tid 0..119, G tid 128..247); buffer bases are
// 992-dword (32-mult) offsets -> same residues. Scalar VALU only (R6/R14:
// packed v2f regressed). Ascending-s order everywhere -> bitwise-identical out.
#define TW 32
#define TH 24
#define LSTR 47          // L stride (==15 mod 32)
#define LROWS 39         // 24 + 6 conv + 9 shift span
#define LPADSZ 1856      // 39*47=1833 padded to 32-mult -> LG base bank-aligned
#define TMS 31           // tmp_T stride (==-1 mod 32)
#define TTSZ (TW * TMS)  // 992 dwords (32-mult)
#define NXT 12
#define NYT 16

#define G0 0.32465246735834974f   // exp(-9/8)
#define G1 0.6065306597126334f    // exp(-4/8)
#define G2 0.8824969025845955f    // exp(-1/8)
#define KS 0.039788735772973836f  // 1/(8*pi)
#define LOG2E 1.4426950408889634f

__device__ __forceinline__ float tap7(const float* v)
{
    return fmaf(G0, v[0] + v[6],
           fmaf(G1, v[1] + v[5],
           fmaf(G2, v[2] + v[4], v[3])));
}

__device__ __forceinline__ void shift_of(int s, int& sx, int& sy)
{
    int t = (s < 55) ? s : s + 1;    // skip (0,0)
    sx = t / 10 - 5;
    sy = t - (t / 10) * 10 - 5;
}

__device__ __forceinline__ void load_tile(const float* __restrict__ img,
                                          int oy0, int ox0, float* L, int tid)
{
    for (int i = tid; i < LROWS * LSTR; i += 256) {
        int r = i / LSTR, c = i - r * LSTR;
        int gr = oy0 + r; if (gr >= HH) gr -= HH;   // circular wrap
        int gc = ox0 + c; if (gc >= WW) gc -= WW;
        L[i] = img[gr * WW + gc];
    }
}

// horizontal 7-tap over inline diff^2; 8 outputs -> transposed tmp (R13 scalar core)
__device__ __forceinline__ void horiz8(const float* __restrict__ Lb,
                                       const float* __restrict__ cA,
                                       float* __restrict__ tb,
                                       int r, int c0, int sx, int sy)
{
    const float* Ls = &Lb[(r + 4 - sy) * LSTR + (c0 + 4 - sx)];
    float v[14];
#pragma unroll
    for (int t = 0; t < 14; ++t) { float d = cA[t] - Ls[t]; v[t] = d * d; }
    float* o = &tb[c0 * TMS + r];
#pragma unroll
    for (int k = 0; k < 8; ++k) o[k * TMS] = tap7(v + k);
}

// vertical 7-tap, 3 outputs from 9 consecutive tmp_T values (R13 scalar core)
__device__ __forceinline__ void vert3(const float* __restrict__ tT, int vx, int vy0, float* D)
{
    const float* t = &tT[vx * TMS + vy0];
    float w[9];
#pragma unroll
    for (int j = 0; j < 9; ++j) w[j] = t[j];
#pragma unroll
    for (int k = 0; k < 3; ++k) D[k] = KS * tap7(w + k);
}

extern "C" __global__ void __launch_bounds__(256, 3)
mind_fused(const float* __restrict__ pred, const float* __restrict__ gt,
           float* __restrict__ out)
{
    __shared__ float LP[LPADSZ];
    __shared__ float LG[LPADSZ];
    __shared__ float tTP[4][TTSZ];   // [par*2 + j] : 2 parities x 2 shifts/period
    __shared__ float tTG[4][TTSZ];
    __shared__ float wred[4];
    const int tid = threadIdx.x;
    const int b = blockIdx.y;
    const int oy0 = ((int)blockIdx.x / NXT) * TH;
    const int ox0 = ((int)blockIdx.x % NXT) * TW;

    load_tile(pred + (size_t)b * HH * WW, oy0, ox0, LP, tid);
    load_tile(gt   + (size_t)b * HH * WW, oy0, ox0, LG, tid);

    // horiz: 120 units/image = 30 rows x 4 col-octets. PURE phases:
    // P on tid 0..119, G on tid 128..247 (no 32-lane phase mixes images).
    const bool hP = tid < 120;
    const bool hG = (tid >= 128) && (tid < 248);
    const bool hasH = hP || hG;
    const int hu = hP ? tid : (tid - 128);
    const int hr = hu >> 2, hc0 = (hu & 3) << 3;
    const float* Lh = hG ? LG : LP;
    float (* const tb)[TTSZ] = hG ? tTG : tTP;

    // vert: all 256 = 32 cols x 8 strips of 3 rows, both images per thread
    const int vx = tid & 31, vy0 = (tid >> 5) * 3;

    __syncthreads();

    float cA[14];
    if (hasH) {
        const float* p = &Lh[(hr + 4) * LSTR + hc0 + 4];
#pragma unroll
        for (int t = 0; t < 14; ++t) cA[t] = p[t];
    }

    // ---- phase 1: V (4 cardinals) and minD over 99 shifts, both images ----
    float dmp[3], vsp[3], dmg[3], vsg[3];
#pragma unroll
    for (int k = 0; k < 3; ++k) { dmp[k] = 1e30f; vsp[k] = 0.f; dmg[k] = 1e30f; vsg[k] = 0.f; }

    for (int sp = 0; sp < NSHIFT; sp += 2) {
        const int par2 = ((sp >> 1) & 1) << 1;
        const bool has2 = (sp + 1 < NSHIFT);   // uniform (last period single)
        int sx0, sy0, sx1, sy1;
        shift_of(sp, sx0, sy0);
        if (has2) shift_of(sp + 1, sx1, sy1);
        if (hasH) {
            horiz8(Lh, cA, tb[par2 + 0], hr, hc0, sx0, sy0);
            if (has2) horiz8(Lh, cA, tb[par2 + 1], hr, hc0, sx1, sy1);
        }
        __syncthreads();   // period buffers ready; parity alternation -> WAR safe
        {
            float Dp[3], Dg[3];
            vert3(tTP[par2 + 0], vx, vy0, Dp);
            vert3(tTG[par2 + 0], vx, vy0, Dg);
            const bool card = (sx0 * sx0 + sy0 * sy0) == 1;
#pragma unroll
            for (int k = 0; k < 3; ++k) {
                dmp[k] = fminf(dmp[k], Dp[k]);
                dmg[k] = fminf(dmg[k], Dg[k]);
                if (card) { vsp[k] += Dp[k]; vsg[k] += Dg[k]; }
            }
        }
        if (has2) {
            float Dp[3], Dg[3];
            vert3(tTP[par2 + 1], vx, vy0, Dp);
            vert3(tTG[par2 + 1], vx, vy0, Dg);
            const bool card = (sx1 * sx1 + sy1 * sy1) == 1;
#pragma unroll
            for (int k = 0; k < 3; ++k) {
                dmp[k] = fminf(dmp[k], Dp[k]);
                dmg[k] = fminf(dmg[k], Dg[k]);
                if (card) { vsp[k] += Dp[k]; vsg[k] += Dg[k]; }
            }
        }
    }

    // loss constants; invalid pixels get rv=0 -> ep=eg=exp2(0)=1 -> |ep-eg|=0
    // exactly, so the phase-2 loop is fully branchless.
    float rvp[3], rvg[3];
#pragma unroll
    for (int k = 0; k < 3; ++k) {
        int oy = oy0 + vy0 + k, ox = ox0 + vx;
        const bool valid = (oy < OUTD) && (ox < OUTD);
        rvp[k] = valid ? LOG2E / (vsp[k] * 0.25f + 1e-5f) : 0.f;
        rvg[k] = valid ? LOG2E / (vsg[k] * 0.25f + 1e-5f) : 0.f;
    }

    __syncthreads();   // phase boundary: protect buffer reuse against last vert read

    // ---- phase 2: recompute D, accumulate |exp2((m-D)*rv)p - (...)g| ----
    float acc = 0.f;
    for (int sp = 0; sp < NSHIFT; sp += 2) {
        const int par2 = ((sp >> 1) & 1) << 1;
        const bool has2 = (sp + 1 < NSHIFT);
        int sx0, sy0, sx1, sy1;
        shift_of(sp, sx0, sy0);
        if (has2) shift_of(sp + 1, sx1, sy1);
        if (hasH) {
            horiz8(Lh, cA, tb[par2 + 0], hr, hc0, sx0, sy0);
            if (has2) horiz8(Lh, cA, tb[par2 + 1], hr, hc0, sx1, sy1);
        }
        __syncthreads();
        {
            float Dp[3], Dg[3];
            vert3(tTP[par2 + 0], vx, vy0, Dp);
            vert3(tTG[par2 + 0], vx, vy0, Dg);
#pragma unroll
            for (int k = 0; k < 3; ++k) {
                float ep = exp2f((dmp[k] - Dp[k]) * rvp[k]);
                float eg = exp2f((dmg[k] - Dg[k]) * rvg[k]);
                acc += fabsf(ep - eg);
            }
        }
        if (has2) {
            float Dp[3], Dg[3];
            vert3(tTP[par2 + 1], vx, vy0, Dp);
            vert3(tTG[par2 + 1], vx, vy0, Dg);
#pragma unroll
            for (int k = 0; k < 3; ++k) {
                float ep = exp2f((dmp[k] - Dp[k]) * rvp[k]);
                float eg = exp2f((dmg[k] - Dg[k]) * rvg[k]);
                acc += fabsf(ep - eg);
            }
        }
    }

#pragma unroll
    for (int off = 32; off > 0; off >>= 1) acc += __shfl_down(acc, off, 64);
    const int lane = tid & 63, wv = tid >> 6;
    if (lane == 0) wred[wv] = acc;
    __syncthreads();
    if (tid == 0) {
        const float SC = (float)(1.0 / 54212400.0);  // 1/(4*370*370*99)
        atomicAdd(out, (wred[0] + wred[1] + wred[2] + wred[3]) * SC);
    }
}

extern "C" void kernel_launch(void* const* d_in, const int* in_sizes, int n_in,
                              void* d_out, int out_size, void* d_ws, size_t ws_size,
                              hipStream_t stream)
{
    (void)in_sizes; (void)n_in; (void)out_size; (void)d_ws; (void)ws_size;
    const float* pred = (const float*)d_in[0];
    const float* gt   = (const float*)d_in[1];
    float* out = (float*)d_out;

    hipMemsetAsync(d_out, 0, sizeof(float), stream);

    dim3 g(NXT * NYT, 4, 1);   // 192 tiles x 4 batch = 768 blocks = 3/CU exact
    mind_fused<<<g, 256, 0, stream>>>(pred, gt, out);
}